// Round 6
// baseline (196.011 us; speedup 1.0000x reference)
//
#include <hip/hip_runtime.h>

#define B_ 512
#define T_ 512
#define C_ 128
#define L_ 80
#define BLANK_ 127
#define EPS_ 1e-7f
#define LN2_ 0.6931471805599453f
#define RING_ 16    // ring depth in 8-row blocks (64 KB LDS)

// raw v_log_f32 (base-2); __log2f collides with glibc math.h reserved names.
#define LOG2F(x) __builtin_amdgcn_logf(x)

// native vector type for __builtin_nontemporal_load (HIP float4 is a struct,
// which the builtin rejects; ext_vector_type is accepted and has .xyzw)
typedef float f32x4_t __attribute__((ext_vector_type(4)));

// DPP cross-lane ops (VALU pipe).
template <int CTRL>
__device__ __forceinline__ int dpp_i(int x) {
  return __builtin_amdgcn_update_dpp(0, x, CTRL, 0xF, 0xF, true);
}
template <int CTRL>
__device__ __forceinline__ float dpp_f(float x) {
  return __int_as_float(
      __builtin_amdgcn_update_dpp(0, __float_as_int(x), CTRL, 0xF, 0xF, true));
}
#define DPP_WSHR1 0x138   // wave shift right 1 == shfl_up(1); lane0 -> 0
#define DPP_XOR1  0xB1    // quad_perm [1,0,3,2]
#define DPP_XOR2  0x4E    // quad_perm [2,3,0,1]
#define DPP_HMIRR 0x141   // row_half_mirror (within 8)
#define DPP_MIRR  0x140   // row_mirror (within 16)

// R5 structure + NON-TEMPORAL streaming loads.
//
// Five schedule variants (1-wave serial, barriered, counted-barrier,
// decoupled, free-running ring) all pinned at kernel ~37-39us: schedule is
// not the variable. Theory: the harness's 512MiB workspace re-poison fills
// the 256MiB LLC with DIRTY lines right before the kernel; every y_pred read
// then allocates an LLC line and evicts a dirty victim -> ~134MB of
// writebacks on top of the 134MB read. 268MB @ ~6.9TB/s = 38.8us = the
// invariant (and R4's decoupled 2-stream variant re-fetched ~134MB more ->
// predicted +19us, measured +18.6us). Fix: nt loads (LLC no-allocate) for
// the once-consumed stream -> no victims -> ~134MB total.
//
// Everything else is the verified (absmax=0) R5 kernel:
//   wave0: DP consumer (forward recurrence, all 512 rows); polls flag[i],
//     gathers 3 cols/row from ring slot i&15, pipelined 1 block ahead;
//     publishes cons=i+1 to return slot credit.
//   waves1-3: producers; own every-3rd block; 2-owned-block register lead;
//     wait slot credit (cons >= j-15), then +EPS, row-sum/log2, ds_write,
//     lgkmcnt(0), release flag[j].
__global__ __launch_bounds__(256) void ctc_fused(
    const int* __restrict__ labels,     // [B,L]
    const float* __restrict__ y_pred,   // [B,T,C]
    float* __restrict__ out)            // [B,1]
{
  const int b = blockIdx.x, tid = threadIdx.x;
  const int wid = tid >> 6, lane = tid & 63;
  const float* gp = y_pred + (size_t)b * T_ * C_;

  __shared__ float ring[RING_ * 1024];  // 16 slots x 8 rows x 128 floats
  __shared__ int   flags[64];           // block i staged?
  __shared__ int   cons;                // blocks fully consumed
  __shared__ float comb[4];             // producers' Sacc partials (1..3)

  if (tid < 64) flags[tid] = 0;
  if (tid == 0) cons = 0;
  __syncthreads();                      // init visible before any traffic

  const bool evenLane = ((lane & 1) == 0);

  if (wid == 0) {
    // ---- DP consumer: static per-lane symbols + skip masks (verified) ----
    // even lane i: states blank / label k1=3i/2 / blank
    // odd  lane i: states label k0=(3i-1)/2 / blank / label k2=k0+1
    auto labAt = [&](int k) -> int {
      return (k >= 0 && k < L_) ? labels[b * L_ + k] : BLANK_;
    };
    int ea, eb;
    float m0, m1, m2;                   // allow-skip masks as 0.0/1.0
    if (evenLane) {
      const int k1 = (3 * lane) >> 1;
      ea = labAt(k1); eb = ea;
      m0 = 0.f; m2 = 0.f;
      m1 = ((k1 < L_) && (k1 == 0 || ea != labAt(k1 - 1))) ? 1.f : 0.f;
    } else {
      const int k0 = (3 * lane - 1) >> 1;
      const int k2 = k0 + 1;
      ea = labAt(k0); eb = labAt(k2);
      m0 = ((k0 < L_) && (k0 == 0 || ea != labAt(k0 - 1))) ? 1.f : 0.f;
      m1 = 0.f;
      m2 = ((k2 < L_) && (eb != ea)) ? 1.f : 0.f;
    }
    // virtual init: one recurrence step from (A0=1@lane0) gives exact alpha(0)
    float A0 = (lane == 0) ? 1.f : 0.f, A1 = 0.f, A2 = 0.f;
    int E = 0;                          // per-lane scale: stored = true * 2^E

    auto waitFlag = [&](int i) {        // uniform: all lanes read same addr
      while (__hip_atomic_load(&flags[i], __ATOMIC_ACQUIRE,
                               __HIP_MEMORY_SCOPE_WORKGROUP) == 0)
        __builtin_amdgcn_s_sleep(2);
    };
    auto consSet = [&](int v) {         // relaxed: freed slot's reads are
      if (lane == 0)                    // 15 blocks stale -> long complete
        __hip_atomic_store(&cons, v, __ATOMIC_RELAXED,
                           __HIP_MEMORY_SCOPE_WORKGROUP);
    };
    auto gath = [&](float (&g)[8], float (&h)[8], float (&p)[8], int i) {
      const float* rs = ring + (i & (RING_ - 1)) * 1024;
      #pragma unroll
      for (int j = 0; j < 8; ++j) {
        g[j] = rs[j * C_ + ea];
        h[j] = rs[j * C_ + eb];
        p[j] = rs[j * C_ + BLANK_];     // same addr all lanes: LDS broadcast
      }
    };
    auto stepG = [&](float (&g)[8], float (&h)[8], float (&p)[8]) {
      const int EL = dpp_i<DPP_WSHR1>(E);   // left lane's exponent (lane0->0)
      const int d = E - EL;             // block-constant reconcile shift
      #pragma unroll
      for (int j = 0; j < 8; ++j) {
        const float p1 = dpp_f<DPP_WSHR1>(A1);   // left A1 (state 3i-2)
        const float p2 = dpp_f<DPP_WSHR1>(A2);   // left A2 (state 3i-1)
        const float p1p = ldexpf(p1, d);
        const float p2p = ldexpf(p2, d);
        const float q0 = evenLane ? p[j] : g[j];
        const float q1 = evenLane ? g[j] : p[j];
        const float q2 = evenLane ? p[j] : h[j];
        const float t0 = q0 * fmaf(m0, p1p, A0 + p2p);
        const float t1 = q1 * fmaf(m1, p2p, A1 + A0);
        const float t2 = q2 * fmaf(m2, A0, A2 + A1);
        A0 = t0; A1 = t1; A2 = t2;
      }
      // per-lane rescale: keep lane max ~2^0, fold into E
      const float mx = fmaxf(fmaxf(A0, A1), A2);
      int ee = (int)((__float_as_uint(mx) >> 23) & 255u) - 127;
      const bool z = (mx == 0.f);
      ee = z ? 0 : ee;
      A0 = ldexpf(A0, -ee); A1 = ldexpf(A1, -ee); A2 = ldexpf(A2, -ee);
      E = z ? EL : (E - ee);            // virgin lanes track left neighbor's E
    };

    // two named gather sets (compile-time indexing only, rule #20);
    // gathers for block i+1 issue before the DP of block i (latency hidden)
    float gaA[8], gbA[8], pbA[8], gaB[8], gbB[8], pbB[8];
    waitFlag(0); gath(gaA, gbA, pbA, 0);
    for (int i = 0; i < 64; i += 2) {
      waitFlag(i + 1); gath(gaB, gbB, pbB, i + 1);
      stepG(gaA, gbA, pbA);             // block i
      consSet(i + 1);
      if (i + 2 < 64) { waitFlag(i + 2); gath(gaA, gbA, pbA, i + 2); }
      stepG(gaB, gbB, pbB);             // block i+1
      consSet(i + 2);
    }

    __syncthreads();                    // the ONLY full barrier (epilogue)

    // loss = ln2 * (S - (log2(A159+A160) - E)); lane 53: A0=s159, A1=s160
    if (lane == 53) {
      const float Stot = comb[1] + comb[2] + comb[3];
      out[b] = LN2_ * (Stot - (LOG2F(A0 + A1) - (float)E));
    }
  } else {
    // ---- producer: every-3rd 8-row block, 2-owned-block register lead ----
    const int w = wid - 1;              // 0..2; owns blocks w, w+3, ...
    const int rgrp = lane >> 3, j16 = lane & 7;
    f32x4_t S0[4], S1[4];
    float Sacc = 0.f;                   // per-lane partial: sum log2(rowsum)

    auto loadB = [&](f32x4_t (&S)[4], int blk) {
      const f32x4_t* src =
          (const f32x4_t*)(gp + (size_t)(8 * blk + rgrp) * C_) + 4 * j16;
      #pragma unroll
      for (int k = 0; k < 4; ++k)
        S[k] = __builtin_nontemporal_load(src + k);   // nt: LLC no-allocate
    };
    auto waitSlot = [&](int j) {        // slot j&15 holds block j-16
      if (j >= RING_) {
        while (__hip_atomic_load(&cons, __ATOMIC_RELAXED,
                                 __HIP_MEMORY_SCOPE_WORKGROUP) < j - (RING_ - 1))
          __builtin_amdgcn_s_sleep(8);
      }
    };
    auto proc = [&](f32x4_t (&S)[4], int j) {  // eps+rowsum+stage+publish
      float* slot = ring + (j & (RING_ - 1)) * 1024;
      f32x4_t* wd = (f32x4_t*)(slot + rgrp * C_ + 16 * j16);
      float s = 0.f;
      #pragma unroll
      for (int k = 0; k < 4; ++k) {
        f32x4_t v = S[k];
        v.x += EPS_; v.y += EPS_; v.z += EPS_; v.w += EPS_;
        wd[k] = v;
        s += (v.x + v.y) + (v.z + v.w);
      }
      s += dpp_f<DPP_XOR1>(s);
      s += dpp_f<DPP_XOR2>(s);
      s += dpp_f<DPP_HMIRR>(s);         // 8 lanes of the row share the sum
      Sacc += LOG2F(s);                 // 8x redundant; divided out at end
      asm volatile("s_waitcnt lgkmcnt(0)" ::: "memory");  // data before flag
      if (lane == 0)
        __hip_atomic_store(&flags[j], 1, __ATOMIC_RELEASE,
                           __HIP_MEMORY_SCOPE_WORKGROUP);
    };

    int j = w;
    loadB(S0, j);
    if (j + 3 < 64) loadB(S1, j + 3);
    while (true) {
      waitSlot(j); proc(S0, j);
      if (j + 6 < 64) loadB(S0, j + 6);
      j += 3;
      if (j >= 64) break;
      waitSlot(j); proc(S1, j);
      if (j + 6 < 64) loadB(S1, j + 6);
      j += 3;
      if (j >= 64) break;
    }

    // denominator partial (each row counted 8x -> *0.125)
    float s = Sacc;
    s += dpp_f<DPP_XOR1>(s);
    s += dpp_f<DPP_XOR2>(s);
    s += dpp_f<DPP_HMIRR>(s);
    s += dpp_f<DPP_MIRR>(s);
    s += __shfl_xor(s, 16, 64);
    s += __shfl_xor(s, 32, 64);
    if (lane == 0) comb[wid] = s * 0.125f;

    __syncthreads();                    // matches consumer's epilogue barrier
  }
}

extern "C" void kernel_launch(void* const* d_in, const int* in_sizes, int n_in,
                              void* d_out, int out_size, void* d_ws, size_t ws_size,
                              hipStream_t stream) {
  const int*   labels = (const int*)d_in[0];    // y_true [B,L]
  const float* y_pred = (const float*)d_in[1];  // y_pred [B,T,C]
  float*       out    = (float*)d_out;          // [B,1]
  ctc_fused<<<dim3(B_), dim3(256), 0, stream>>>(labels, y_pred, out);
}